// Round 13
// baseline (209.669 us; speedup 1.0000x reference)
//
#include <hip/hip_runtime.h>
#include <math.h>

// FusedAttentionWithRPB round 13: r12 structure with the semaphore-init bug
// fixed (hipMemsetAsync zeroes all 384 counters; r12 only zeroed 256 of them
// from a 256-thread block -> bh>=21,qj>=4 rows never merged).
//  - r9 main loop (best known): KA async gl16 dbuf, V frags global-direct,
//    one barrier/step, DPP softmax, bias-as-MFMA (one-hot augmented QK^T)
//  - combine FUSED via last-arriver agent-scope atomic
//  - prep: KA rows + LDS-transposed Vt tiles

constexpr int Bc = 4, Hc = 8, Sc = 1024, Dc = 64;
constexpr int NT = 256;

constexpr size_t KA_BYTES   = (size_t)32 * 1024 * 256;            // 8 MB
constexpr size_t VT_BYTES   = (size_t)32 * 16 * 64 * 128;         // 4 MB
constexpr size_t PART_OFF   = KA_BYTES + VT_BYTES;
constexpr size_t PART_BYTES = (size_t)32 * 12 * 3 * 64 * 66 * sizeof(float);
constexpr size_t CNT_OFF    = PART_OFF + PART_BYTES;
constexpr int    NCNT       = 32 * 12;
constexpr size_t WS_SPLIT   = CNT_OFF + NCNT * sizeof(int);

typedef __attribute__((ext_vector_type(8))) short bf16x8;
typedef __attribute__((ext_vector_type(4))) float f32x4;

// chunk tables: cid -> (qi, ktb, kte, part), heavy-first (LPT)  [r9, validated]
__device__ __constant__ signed char CQI[32] =
  {15,11,11,10,15,15,14,14,14,13,13,12,10, 9, 9, 8,13,12,12, 8, 7, 7, 6, 3, 6, 5, 5, 4, 2, 4, 1, 0};
__device__ __constant__ signed char CKTB[32] =
  {10, 0, 6, 5, 0, 5, 0, 5,10, 4, 9, 8, 0, 0, 5, 4, 0, 0, 4, 0, 0, 4, 3, 0, 0, 0, 3, 2, 0, 0, 0, 0};
__device__ __constant__ signed char CKTE[32] =
  {16, 6,12,11, 5,10, 5,10,15, 9,14,13, 5, 5,10, 9, 4, 4, 8, 4, 4, 8, 7, 4, 3, 3, 6, 5, 3, 2, 2, 1};
__device__ __constant__ signed char CPT[32] =
  { 2, 0, 1, 1, 0, 1, 0, 1, 2, 1, 2, 2, 0, 0, 1, 1, 0, 0, 1, 0, 0, 1, 1, 0, 0, 0, 1, 1, 0, 0, 0, 0};

__device__ __forceinline__ unsigned short f2bf(float f) {
  union { float f; unsigned u; } x; x.f = f;
  unsigned r = x.u + 0x7FFFu + ((x.u >> 16) & 1u);
  return (unsigned short)(r >> 16);
}
__device__ __forceinline__ bf16x8 pack8(float4 a, float4 b) {
  bf16x8 r;
  r[0] = (short)f2bf(a.x); r[1] = (short)f2bf(a.y);
  r[2] = (short)f2bf(a.z); r[3] = (short)f2bf(a.w);
  r[4] = (short)f2bf(b.x); r[5] = (short)f2bf(b.y);
  r[6] = (short)f2bf(b.z); r[7] = (short)f2bf(b.w);
  return r;
}
__device__ __forceinline__ float4 sc4(float4 a, float s) {
  return make_float4(a.x*s, a.y*s, a.z*s, a.w*s);
}
// swizzled byte offset inside a 64x64 bf16 tile (128B rows) for Ps
__device__ __forceinline__ int swzb(int row, int col) {
  return ((row << 7) + (col << 1)) ^ ((row & 7) << 4);
}
template<int C>
__device__ __forceinline__ float dppf(float x) {
  return __int_as_float(__builtin_amdgcn_update_dpp(
      __float_as_int(x), __float_as_int(x), C, 0xF, 0xF, false));
}
__device__ __forceinline__ float red_max16(float x) {
  x = fmaxf(x, dppf<0xB1>(x));  x = fmaxf(x, dppf<0x4E>(x));
  x = fmaxf(x, dppf<0x141>(x)); x = fmaxf(x, dppf<0x140>(x));
  return x;
}
__device__ __forceinline__ float red_sum16(float x) {
  x += dppf<0xB1>(x);  x += dppf<0x4E>(x);
  x += dppf<0x141>(x); x += dppf<0x140>(x);
  return x;
}
__device__ __forceinline__ void gl16(const void* g, void* l) {
  __builtin_amdgcn_global_load_lds(
      (const __attribute__((address_space(1))) void*)g,
      (__attribute__((address_space(3))) void*)l, 16, 0, 0);
}

// ---- fused pre-pass: blocks 0-511 KA rows, 512-1023 Vt tiles (LDS transpose).
// KA row (bh,key): 16 slots of 16B; logical 0-7 = K dims, 8-11 = x-bias cols,
// 12-15 = y-bias cols; physical slot = logical ^ (key&7).
// Vt row (bh,tile,d): 8 slots of 16B; logical s = keys [8s,8s+8); phys = s^(d&7).
__global__ __launch_bounds__(256) void prep(
    const float* __restrict__ kg, const float* __restrict__ vg,
    const int* __restrict__ px, const int* __restrict__ py,
    const float* __restrict__ bx, const float* __restrict__ by,
    unsigned short* __restrict__ wsKA, unsigned short* __restrict__ wsVt)
{
  __shared__ float tile[64 * 68];
  const int t = threadIdx.x;
  if (blockIdx.x < 512) {
    const int g = blockIdx.x * 64 + (t >> 2);
    const int p = t & 3;
    const int bh = g >> 10, key = g & 1023;
    const int b = bh >> 3, h = bh & 7;
    const float* ksrc = kg + ((size_t)bh * Sc + key) * Dc + p * 16;
    float4 f0 = ((const float4*)ksrc)[0], f1 = ((const float4*)ksrc)[1];
    float4 f2 = ((const float4*)ksrc)[2], f3 = ((const float4*)ksrc)[3];
    unsigned short* rowp = wsKA + (size_t)g * 128;
    const int rx = key & 7;
    *(bf16x8*)(rowp + (((2*p)   ^ rx) << 3)) = pack8(f0, f1);
    *(bf16x8*)(rowp + (((2*p+1) ^ rx) << 3)) = pack8(f2, f3);
    const int kx = px[b * Sc + key], ky = py[b * Sc + key];
    bf16x8 xv, yv;
    #pragma unroll
    for (int m = 0; m < 8; ++m) {
      int ix = 8*p + m - kx; ix = ix < -30 ? -30 : (ix > 30 ? 30 : ix);
      int iy = 8*p + m - ky; iy = iy < -30 ? -30 : (iy > 30 ? 30 : iy);
      xv[m] = (short)f2bf(bx[(ix + 30) * Hc + h]);
      yv[m] = (short)f2bf(by[(iy + 30) * Hc + h]);
    }
    *(bf16x8*)(rowp + (((8  + p) ^ rx) << 3)) = xv;
    *(bf16x8*)(rowp + (((12 + p) ^ rx) << 3)) = yv;
  } else {
    const int bid = blockIdx.x - 512;
    const int bh = bid >> 4, tt = bid & 15;
    // coalesced read of the 64x64 f32 V tile into LDS
    const int row = t >> 2, c4 = t & 3;
    const float4* src = (const float4*)(vg + ((size_t)bh * Sc + tt*64 + row) * Dc + c4*16);
    #pragma unroll
    for (int jj = 0; jj < 4; ++jj)
      *(float4*)&tile[row * 68 + c4*16 + 4*jj] = src[jj];
    __syncthreads();
    // transposed write: thread (d, chunk-group)
    const int d = t & 63, cg = t >> 6;
    unsigned short* rowp = wsVt + (((size_t)bh * 16 + tt) * 64 + d) * 64;
    #pragma unroll
    for (int cc = 0; cc < 2; ++cc) {
      const int c = 2*cg + cc;
      bf16x8 vv;
      #pragma unroll
      for (int jj = 0; jj < 8; ++jj)
        vv[jj] = (short)f2bf(tile[(8*c + jj) * 68 + d]);
      *(bf16x8*)(rowp + ((c ^ (d & 7)) << 3)) = vv;
    }
  }
}

// ---- main kernel (r9 loop verbatim; fused-merge epilogue)
__global__ __launch_bounds__(NT, 3) void attn_rpb_mfma12(
    const float* __restrict__ qg,
    const int* __restrict__ px, const int* __restrict__ py, const int* __restrict__ pz,
    const float* __restrict__ bz,
    const unsigned short* __restrict__ wsKA, const unsigned short* __restrict__ wsVt,
    float* __restrict__ outg, float* __restrict__ wsPart, int* cnt, int mode)
{
  int qi, ktb, kte, part, np, bh;
  {
    const int j = blockIdx.x;
    if (mode == 0) {
      const int idx = j & 255; bh = idx >> 3; const int r3 = idx & 7;
      qi = (j < 256) ? (15 - r3) : r3;
      ktb = 0; kte = qi + 1; part = 0; np = 1;
    } else {
      bh = j & 31;
      const int cid = j >> 5;
      qi = CQI[cid]; ktb = CKTB[cid]; kte = CKTE[cid]; part = CPT[cid];
      np = (qi < 4) ? 1 : ((qi < 12) ? 2 : 3);
    }
  }
  const int h = bh & 7, b = bh >> 3;

  __shared__ unsigned short KAb[2][64 * 128];   // 32 KB, async dbuf
  __shared__ unsigned short Ps[64 * 64];        // 8 KB, wave-private rows
  __shared__ float BZ2[256];
  __shared__ int oldc;

  const int t  = threadIdx.x;
  const int w  = t >> 6;
  const int l  = t & 63;
  const int lg = l >> 4;
  const int lr = l & 15;
  const size_t bhOff = (size_t)bh * Sc;
  const int q0 = qi * 64;

  const char* kaSrc = (const char*)wsKA;
  const char* vtSrc = (const char*)wsVt;

  // ---- prologue: async-stage KA[ktb]; tables; Q/one-hot frags -> regs
  {
    const char* srcK = kaSrc + ((size_t)(bh*1024 + ktb*64)) * 256 + w*4096 + l*16;
    char* dstK = (char*)KAb[0] + w*4096;   // wave-uniform base (+lane*16 by HW)
    #pragma unroll
    for (int jj = 0; jj < 4; ++jj) gl16(srcK + jj*1024, dstK + jj*1024);
  }
  {
    int dzz = (t >> 4) - (t & 15); dzz = dzz < -10 ? -10 : (dzz > 10 ? 10 : dzz);
    BZ2[t] = bz[(dzz + 10) * Hc + h];
  }
  const int myrow = q0 + 16*w + lr;
  bf16x8 aq[4];
  {
    const float* qrow = qg + (bhOff + myrow) * Dc;
    #pragma unroll
    for (int ks = 0; ks < 2; ++ks) {
      float4 f0 = *(const float4*)(qrow + 32*ks + 8*lg);
      float4 f1 = *(const float4*)(qrow + 32*ks + 8*lg + 4);
      aq[ks] = pack8(sc4(f0, 0.125f), sc4(f1, 0.125f));
    }
    const int qxr = px[b*Sc + myrow], qyr = py[b*Sc + myrow];
    const short one = (short)0x3F80;
    #pragma unroll
    for (int m = 0; m < 8; ++m) {
      aq[2][m] = (qxr == 8*lg + m) ? one : (short)0;
      aq[3][m] = (qyr == 8*lg + m) ? one : (short)0;
    }
  }
  int rowg[4], qz16[4];
  #pragma unroll
  for (int r = 0; r < 4; ++r) {
    const int rl = 16*w + 4*lg + r;
    rowg[r] = q0 + rl;
    qz16[r] = pz[b*Sc + q0 + rl] << 4;
  }

  float mrow[4], lsum[4];
  f32x4 O[4];
  const f32x4 zero4 = {0.f, 0.f, 0.f, 0.f};
  #pragma unroll
  for (int r = 0; r < 4; ++r) { mrow[r] = -INFINITY; lsum[r] = 0.f; }
  #pragma unroll
  for (int nt_ = 0; nt_ < 4; ++nt_) O[nt_] = zero4;

  __syncthreads();   // KA[ktb] staged (vmcnt drained), BZ2 visible

  for (int kt = ktb; kt < kte; ++kt) {
    const int cur = (kt - ktb) & 1;
    const int nb  = cur ^ 1;
    const bool pf = (kt + 1 < kte);
    const int k0 = kt * 64;

    // ---- early issues: KA[kt+1] async -> other buffer; V frags + kz -> regs
    if (pf) {
      const char* srcK = kaSrc + ((size_t)(bh*1024 + (kt+1)*64)) * 256 + w*4096 + l*16;
      char* dstK = (char*)KAb[nb] + w*4096;
      #pragma unroll
      for (int jj = 0; jj < 4; ++jj) gl16(srcK + jj*1024, dstK + jj*1024);
    }
    bf16x8 vv[8];
    {
      const char* vtile = vtSrc + ((size_t)(bh*16 + kt)) * 8192;
      #pragma unroll
      for (int nt_ = 0; nt_ < 4; ++nt_) {
        #pragma unroll
        for (int ks = 0; ks < 2; ++ks)
          vv[nt_*2 + ks] = *(const bf16x8*)(vtile + (16*nt_ + lr) * 128
                                            + ((((4*ks + lg) ^ (lr & 7))) << 4));
      }
    }
    int kzv[4];
    #pragma unroll
    for (int ct = 0; ct < 4; ++ct) kzv[ct] = pz[b*Sc + k0 + 16*ct + lr];

    // ---- S = [Q|onehot] x KA^T  (K=128, 16 MFMA)
    f32x4 s[4];
    #pragma unroll
    for (int ct = 0; ct < 4; ++ct) {
      s[ct] = zero4;
      const char* kab = (const char*)KAb[cur] + (16*ct + lr) * 256;
      #pragma unroll
      for (int ks = 0; ks < 4; ++ks) {
        bf16x8 bk = *(const bf16x8*)(kab + ((((4*ks + lg) ^ (lr & 7))) << 4));
        s[ct] = __builtin_amdgcn_mfma_f32_16x16x32_bf16(aq[ks], bk, s[ct], 0, 0, 0);
      }
    }

    // ---- z-bias + causal mask + online softmax
    const bool diag = (kt == qi);
    #pragma unroll
    for (int ct = 0; ct < 4; ++ct) {
      const int colg = k0 + 16*ct + lr;
      #pragma unroll
      for (int r = 0; r < 4; ++r) {
        float val = s[ct][r] + BZ2[qz16[r] | kzv[ct]];
        if (diag && colg > rowg[r]) val = -INFINITY;
        s[ct][r] = val;
      }
    }
    float rmax[4];
    #pragma unroll
    for (int r = 0; r < 4; ++r) {
      rmax[r] = fmaxf(fmaxf(s[0][r], s[1][r]), fmaxf(s[2][r], s[3][r]));
      rmax[r] = red_max16(rmax[r]);
    }
    float alpha[4];
    #pragma unroll
    for (int r = 0; r < 4; ++r) {
      const float mn = fmaxf(mrow[r], rmax[r]);
      alpha[r] = __expf(mrow[r] - mn);
      mrow[r] = mn;
    }
    #pragma unroll
    for (int ct = 0; ct < 4; ++ct) {
      #pragma unroll
      for (int r = 0; r < 4; ++r)
        s[ct][r] = __expf(s[ct][r] - mrow[r]);
    }
    #pragma unroll
    for (int r = 0; r < 4; ++r) {
      float ps = (s[0][r] + s[1][r]) + (s[2][r] + s[3][r]);
      ps = red_sum16(ps);
      lsum[r] = lsum[r] * alpha[r] + ps;
    }
    #pragma unroll
    for (int nt_ = 0; nt_ < 4; ++nt_) {
      #pragma unroll
      for (int r = 0; r < 4; ++r) O[nt_][r] *= alpha[r];
    }

    // ---- P -> bf16 -> Ps (wave-private rows; same-wave ordering suffices)
    #pragma unroll
    for (int ct = 0; ct < 4; ++ct) {
      #pragma unroll
      for (int r = 0; r < 4; ++r)
        *(unsigned short*)((char*)Ps + swzb(16*w + 4*lg + r, 16*ct + lr)) = f2bf(s[ct][r]);
    }
    bf16x8 pa[2];
    pa[0] = *(const bf16x8*)((const char*)Ps + swzb(16*w + lr, 8*lg));
    pa[1] = *(const bf16x8*)((const char*)Ps + swzb(16*w + lr, 8*lg + 32));

    // ---- O += P V (V fragments already in regs)
    #pragma unroll
    for (int nt_ = 0; nt_ < 4; ++nt_) {
      #pragma unroll
      for (int ks = 0; ks < 2; ++ks)
        O[nt_] = __builtin_amdgcn_mfma_f32_16x16x32_bf16(pa[ks], vv[nt_*2 + ks], O[nt_], 0, 0, 0);
    }

    __syncthreads();   // one barrier/step: drains KA[nb] gl16, flips buffers
  }

  // ---- epilogue
  if (np == 1) {
    #pragma unroll
    for (int r = 0; r < 4; ++r) {
      const float inv = 1.0f / lsum[r];
      #pragma unroll
      for (int nt_ = 0; nt_ < 4; ++nt_)
        outg[(bhOff + q0 + 16*w + 4*lg + r) * Dc + 16*nt_ + lr] = O[nt_][r] * inv;
    }
    return;
  }

  // split: write partials, then last-arriver merges (fused combine)
  const int qj = qi - 4;
  float* base0 = wsPart + (((size_t)bh * 12 + qj) * 3) * 64 * 66;
  {
    float* basep = base0 + (size_t)part * 64 * 66;
    #pragma unroll
    for (int r = 0; r < 4; ++r) {
      float* rowp = basep + (16*w + 4*lg + r) * 66;
      #pragma unroll
      for (int nt_ = 0; nt_ < 4; ++nt_)
        rowp[16*nt_ + lr] = O[nt_][r];
      if (lr == 0) { rowp[64] = mrow[r]; rowp[65] = lsum[r]; }
    }
  }
  __threadfence();     // device-scope release of this thread's partial writes
  __syncthreads();     // all block threads' writes ordered before the atomic
  if (t == 0)
    oldc = __hip_atomic_fetch_add(&cnt[bh * 12 + qj], 1,
                                  __ATOMIC_ACQ_REL, __HIP_MEMORY_SCOPE_AGENT);
  __syncthreads();
  if (oldc == np - 1) {
    // merge np partials for this (bh, qi): 64 rows x 64 d
    for (int i = t; i < 4096; i += NT) {
      const int row = i >> 6, d = i & 63;
      const float* r0 = base0 + (size_t)row * 66;
      float m = -INFINITY;
      for (int p = 0; p < np; ++p) m = fmaxf(m, r0[(size_t)p * 4224 + 64]);
      float lc = 0.f, o = 0.f;
      for (int p = 0; p < np; ++p) {
        const float wp = __expf(r0[(size_t)p * 4224 + 64] - m);
        lc += r0[(size_t)p * 4224 + 65] * wp;
        o  += r0[(size_t)p * 4224 + d] * wp;
      }
      outg[(bhOff + q0 + row) * Dc + d] = o / lc;
    }
  }
}

extern "C" void kernel_launch(void* const* d_in, const int* in_sizes, int n_in,
                              void* d_out, int out_size, void* d_ws, size_t ws_size,
                              hipStream_t stream) {
  const float* q  = (const float*)d_in[0];
  const float* k  = (const float*)d_in[1];
  const float* v  = (const float*)d_in[2];
  const int*   px = (const int*)d_in[3];
  const int*   py = (const int*)d_in[4];
  const int*   pz = (const int*)d_in[5];
  const float* bx = (const float*)d_in[6];
  const float* by = (const float*)d_in[7];
  const float* bz = (const float*)d_in[8];
  float* out = (float*)d_out;

  unsigned short* wsKA = (unsigned short*)d_ws;
  unsigned short* wsVt = (unsigned short*)((char*)d_ws + KA_BYTES);
  float* wsPart = (float*)((char*)d_ws + PART_OFF);
  const bool split = (ws_size >= WS_SPLIT);
  int* cnt = split ? (int*)((char*)d_ws + CNT_OFF) : nullptr;

  if (split) hipMemsetAsync(cnt, 0, NCNT * sizeof(int), stream);  // ALL 384 ctrs
  prep<<<1024, 256, 0, stream>>>(k, v, px, py, bx, by, wsKA, wsVt);

  if (split) {
    attn_rpb_mfma12<<<1024, NT, 0, stream>>>(q, px, py, pz, bz, wsKA, wsVt, out, wsPart, cnt, 1);
  } else {
    attn_rpb_mfma12<<<512, NT, 0, stream>>>(q, px, py, pz, bz, wsKA, wsVt, out, wsPart, cnt, 0);
  }
}

// Round 14
// 42.046 us; speedup vs baseline: 4.9867x; 4.9867x over previous
//
#include <hip/hip_runtime.h>
#include <math.h>

// FusedAttentionWithRPB round 14: r9 structure (best known, 42.0us) with
// fragment-major Vt layout in d_ws so per-step V loads are fully coalesced
// (r9 had 128B-stride lanes -> ~32 cache lines per load; r11 showed this
// scatter amplification is expensive). Separate combine kernel (r13 proved
// device-scope fences/atomics in-kernel cost >> a launch boundary).

constexpr int Bc = 4, Hc = 8, Sc = 1024, Dc = 64;
constexpr int NT = 256;

constexpr size_t KA_BYTES   = (size_t)32 * 1024 * 256;            // 8 MB
constexpr size_t VT_BYTES   = (size_t)32 * 16 * 64 * 128;         // 4 MB
constexpr size_t PART_OFF   = KA_BYTES + VT_BYTES;
constexpr size_t PART_BYTES = (size_t)32 * 12 * 3 * 64 * 66 * sizeof(float);
constexpr size_t WS_SPLIT   = PART_OFF + PART_BYTES;

typedef __attribute__((ext_vector_type(8))) short bf16x8;
typedef __attribute__((ext_vector_type(4))) float f32x4;

// chunk tables: cid -> (qi, ktb, kte, part), heavy-first (LPT)  [r9, validated]
__device__ __constant__ signed char CQI[32] =
  {15,11,11,10,15,15,14,14,14,13,13,12,10, 9, 9, 8,13,12,12, 8, 7, 7, 6, 3, 6, 5, 5, 4, 2, 4, 1, 0};
__device__ __constant__ signed char CKTB[32] =
  {10, 0, 6, 5, 0, 5, 0, 5,10, 4, 9, 8, 0, 0, 5, 4, 0, 0, 4, 0, 0, 4, 3, 0, 0, 0, 3, 2, 0, 0, 0, 0};
__device__ __constant__ signed char CKTE[32] =
  {16, 6,12,11, 5,10, 5,10,15, 9,14,13, 5, 5,10, 9, 4, 4, 8, 4, 4, 8, 7, 4, 3, 3, 6, 5, 3, 2, 2, 1};
__device__ __constant__ signed char CPT[32] =
  { 2, 0, 1, 1, 0, 1, 0, 1, 2, 1, 2, 2, 0, 0, 1, 1, 0, 0, 1, 0, 0, 1, 1, 0, 0, 0, 1, 1, 0, 0, 0, 0};

__device__ __forceinline__ unsigned short f2bf(float f) {
  union { float f; unsigned u; } x; x.f = f;
  unsigned r = x.u + 0x7FFFu + ((x.u >> 16) & 1u);
  return (unsigned short)(r >> 16);
}
__device__ __forceinline__ bf16x8 pack8(float4 a, float4 b) {
  bf16x8 r;
  r[0] = (short)f2bf(a.x); r[1] = (short)f2bf(a.y);
  r[2] = (short)f2bf(a.z); r[3] = (short)f2bf(a.w);
  r[4] = (short)f2bf(b.x); r[5] = (short)f2bf(b.y);
  r[6] = (short)f2bf(b.z); r[7] = (short)f2bf(b.w);
  return r;
}
__device__ __forceinline__ float4 sc4(float4 a, float s) {
  return make_float4(a.x*s, a.y*s, a.z*s, a.w*s);
}
// swizzled byte offset inside a 64x64 bf16 tile (128B rows) for Ps
__device__ __forceinline__ int swzb(int row, int col) {
  return ((row << 7) + (col << 1)) ^ ((row & 7) << 4);
}
template<int C>
__device__ __forceinline__ float dppf(float x) {
  return __int_as_float(__builtin_amdgcn_update_dpp(
      __float_as_int(x), __float_as_int(x), C, 0xF, 0xF, false));
}
__device__ __forceinline__ float red_max16(float x) {
  x = fmaxf(x, dppf<0xB1>(x));  x = fmaxf(x, dppf<0x4E>(x));
  x = fmaxf(x, dppf<0x141>(x)); x = fmaxf(x, dppf<0x140>(x));
  return x;
}
__device__ __forceinline__ float red_sum16(float x) {
  x += dppf<0xB1>(x);  x += dppf<0x4E>(x);
  x += dppf<0x141>(x); x += dppf<0x140>(x);
  return x;
}
__device__ __forceinline__ void gl16(const void* g, void* l) {
  __builtin_amdgcn_global_load_lds(
      (const __attribute__((address_space(1))) void*)g,
      (__attribute__((address_space(3))) void*)l, 16, 0, 0);
}

// ---- fused pre-pass: blocks 0-511 KA rows, 512-1023 Vt tiles (LDS transpose).
// KA row (bh,key): 16 slots of 16B; logical 0-7 = K dims, 8-11 = x-bias cols,
// 12-15 = y-bias cols; physical slot = logical ^ (key&7).
// Vt tile (bh,kt): FRAGMENT-MAJOR, 8 frags x 1KB. Fragment f = nt*2+ks holds,
// at lane l = 16*lg+lr (16B each): V[keys 32ks+8lg..+8)[d = 16nt+lr] in bf16.
__global__ __launch_bounds__(256) void prep(
    const float* __restrict__ kg, const float* __restrict__ vg,
    const int* __restrict__ px, const int* __restrict__ py,
    const float* __restrict__ bx, const float* __restrict__ by,
    unsigned short* __restrict__ wsKA, unsigned short* __restrict__ wsVt)
{
  __shared__ float tile[64 * 68];
  const int t = threadIdx.x;
  if (blockIdx.x < 512) {
    const int g = blockIdx.x * 64 + (t >> 2);
    const int p = t & 3;
    const int bh = g >> 10, key = g & 1023;
    const int b = bh >> 3, h = bh & 7;
    const float* ksrc = kg + ((size_t)bh * Sc + key) * Dc + p * 16;
    float4 f0 = ((const float4*)ksrc)[0], f1 = ((const float4*)ksrc)[1];
    float4 f2 = ((const float4*)ksrc)[2], f3 = ((const float4*)ksrc)[3];
    unsigned short* rowp = wsKA + (size_t)g * 128;
    const int rx = key & 7;
    *(bf16x8*)(rowp + (((2*p)   ^ rx) << 3)) = pack8(f0, f1);
    *(bf16x8*)(rowp + (((2*p+1) ^ rx) << 3)) = pack8(f2, f3);
    const int kx = px[b * Sc + key], ky = py[b * Sc + key];
    bf16x8 xv, yv;
    #pragma unroll
    for (int m = 0; m < 8; ++m) {
      int ix = 8*p + m - kx; ix = ix < -30 ? -30 : (ix > 30 ? 30 : ix);
      int iy = 8*p + m - ky; iy = iy < -30 ? -30 : (iy > 30 ? 30 : iy);
      xv[m] = (short)f2bf(bx[(ix + 30) * Hc + h]);
      yv[m] = (short)f2bf(by[(iy + 30) * Hc + h]);
    }
    *(bf16x8*)(rowp + (((8  + p) ^ rx) << 3)) = xv;
    *(bf16x8*)(rowp + (((12 + p) ^ rx) << 3)) = yv;
  } else {
    const int bid = blockIdx.x - 512;
    const int bh = bid >> 4, tt = bid & 15;
    // coalesced read of the 64x64 f32 V tile into LDS
    const int row = t >> 2, c4 = t & 3;
    const float4* src = (const float4*)(vg + ((size_t)bh * Sc + tt*64 + row) * Dc + c4*16);
    #pragma unroll
    for (int jj = 0; jj < 4; ++jj)
      *(float4*)&tile[row * 68 + c4*16 + 4*jj] = src[jj];
    __syncthreads();
    // fragment-major transposed write: thread (d, cg) emits chunks c=2cg,2cg+1
    const int d = t & 63, cg = t >> 6;
    const int nt_ = d >> 4, lr = d & 15;
    unsigned short* tbase = wsVt + (size_t)(bh * 16 + tt) * 4096;
    #pragma unroll
    for (int cc = 0; cc < 2; ++cc) {
      const int c = 2*cg + cc;            // keys [8c, 8c+8)
      const int ks = c >> 2, lg = c & 3;
      bf16x8 vv;
      #pragma unroll
      for (int jj = 0; jj < 8; ++jj)
        vv[jj] = (short)f2bf(tile[(8*c + jj) * 68 + d]);
      *(bf16x8*)(tbase + (nt_*2 + ks) * 512 + (16*lg + lr) * 8) = vv;
    }
  }
}

// ---- main kernel (r9 loop; fragment-major V loads)
__global__ __launch_bounds__(NT, 3) void attn_rpb_mfma13(
    const float* __restrict__ qg,
    const int* __restrict__ px, const int* __restrict__ py, const int* __restrict__ pz,
    const float* __restrict__ bz,
    const unsigned short* __restrict__ wsKA, const unsigned short* __restrict__ wsVt,
    float* __restrict__ outg, float* __restrict__ wsPart, int mode)
{
  int qi, ktb, kte, part, np, bh;
  {
    const int j = blockIdx.x;
    if (mode == 0) {
      const int idx = j & 255; bh = idx >> 3; const int r3 = idx & 7;
      qi = (j < 256) ? (15 - r3) : r3;
      ktb = 0; kte = qi + 1; part = 0; np = 1;
    } else {
      bh = j & 31;
      const int cid = j >> 5;
      qi = CQI[cid]; ktb = CKTB[cid]; kte = CKTE[cid]; part = CPT[cid];
      np = (qi < 4) ? 1 : ((qi < 12) ? 2 : 3);
    }
  }
  const int h = bh & 7, b = bh >> 3;

  __shared__ unsigned short KAb[2][64 * 128];   // 32 KB, async dbuf
  __shared__ unsigned short Ps[64 * 64];        // 8 KB, wave-private rows
  __shared__ float BZ2[256];

  const int t  = threadIdx.x;
  const int w  = t >> 6;
  const int l  = t & 63;
  const int lg = l >> 4;
  const int lr = l & 15;
  const size_t bhOff = (size_t)bh * Sc;
  const int q0 = qi * 64;

  const char* kaSrc = (const char*)wsKA;
  const char* vtSrc = (const char*)wsVt;

  // ---- prologue: async-stage KA[ktb]; tables; Q/one-hot frags -> regs
  {
    const char* srcK = kaSrc + ((size_t)(bh*1024 + ktb*64)) * 256 + w*4096 + l*16;
    char* dstK = (char*)KAb[0] + w*4096;   // wave-uniform base (+lane*16 by HW)
    #pragma unroll
    for (int jj = 0; jj < 4; ++jj) gl16(srcK + jj*1024, dstK + jj*1024);
  }
  {
    int dzz = (t >> 4) - (t & 15); dzz = dzz < -10 ? -10 : (dzz > 10 ? 10 : dzz);
    BZ2[t] = bz[(dzz + 10) * Hc + h];
  }
  const int myrow = q0 + 16*w + lr;
  bf16x8 aq[4];
  {
    const float* qrow = qg + (bhOff + myrow) * Dc;
    #pragma unroll
    for (int ks = 0; ks < 2; ++ks) {
      float4 f0 = *(const float4*)(qrow + 32*ks + 8*lg);
      float4 f1 = *(const float4*)(qrow + 32*ks + 8*lg + 4);
      aq[ks] = pack8(sc4(f0, 0.125f), sc4(f1, 0.125f));
    }
    const int qxr = px[b*Sc + myrow], qyr = py[b*Sc + myrow];
    const short one = (short)0x3F80;
    #pragma unroll
    for (int m = 0; m < 8; ++m) {
      aq[2][m] = (qxr == 8*lg + m) ? one : (short)0;
      aq[3][m] = (qyr == 8*lg + m) ? one : (short)0;
    }
  }
  int rowg[4], qz16[4];
  #pragma unroll
  for (int r = 0; r < 4; ++r) {
    const int rl = 16*w + 4*lg + r;
    rowg[r] = q0 + rl;
    qz16[r] = pz[b*Sc + q0 + rl] << 4;
  }

  float mrow[4], lsum[4];
  f32x4 O[4];
  const f32x4 zero4 = {0.f, 0.f, 0.f, 0.f};
  #pragma unroll
  for (int r = 0; r < 4; ++r) { mrow[r] = -INFINITY; lsum[r] = 0.f; }
  #pragma unroll
  for (int nt_ = 0; nt_ < 4; ++nt_) O[nt_] = zero4;

  __syncthreads();   // KA[ktb] staged (vmcnt drained), BZ2 visible

  for (int kt = ktb; kt < kte; ++kt) {
    const int cur = (kt - ktb) & 1;
    const int nb  = cur ^ 1;
    const bool pf = (kt + 1 < kte);
    const int k0 = kt * 64;

    // ---- early issues: KA[kt+1] async -> other buffer; V frags + kz -> regs
    if (pf) {
      const char* srcK = kaSrc + ((size_t)(bh*1024 + (kt+1)*64)) * 256 + w*4096 + l*16;
      char* dstK = (char*)KAb[nb] + w*4096;
      #pragma unroll
      for (int jj = 0; jj < 4; ++jj) gl16(srcK + jj*1024, dstK + jj*1024);
    }
    bf16x8 vv[8];
    {
      // fragment-major: 8 fully-coalesced 1KB loads (lane l reads frag f at l*16)
      const char* vtile = vtSrc + ((size_t)(bh*16 + kt)) * 8192 + l*16;
      #pragma unroll
      for (int f = 0; f < 8; ++f)
        vv[f] = *(const bf16x8*)(vtile + f*1024);
    }
    int kzv[4];
    #pragma unroll
    for (int ct = 0; ct < 4; ++ct) kzv[ct] = pz[b*Sc + k0 + 16*ct + lr];

    // ---- S = [Q|onehot] x KA^T  (K=128, 16 MFMA)
    f32x4 s[4];
    #pragma unroll
    for (int ct = 0; ct < 4; ++ct) {
      s[ct] = zero4;
      const char* kab = (const char*)KAb[cur] + (16*ct + lr) * 256;
      #pragma unroll
      for (int ks = 0; ks < 4; ++ks) {
        bf16x8 bk = *(const bf16x8*)(kab + ((((4*ks + lg) ^ (lr & 7))) << 4));
        s[ct] = __builtin_amdgcn_mfma_f32_16x16x32_bf16(aq[ks], bk, s[ct], 0, 0, 0);
      }
    }

    // ---- z-bias + causal mask + online softmax
    const bool diag = (kt == qi);
    #pragma unroll
    for (int ct = 0; ct < 4; ++ct) {
      const int colg = k0 + 16*ct + lr;
      #pragma unroll
      for (int r = 0; r < 4; ++r) {
        float val = s[ct][r] + BZ2[qz16[r] | kzv[ct]];
        if (diag && colg > rowg[r]) val = -INFINITY;
        s[ct][r] = val;
      }
    }
    float rmax[4];
    #pragma unroll
    for (int r = 0; r < 4; ++r) {
      rmax[r] = fmaxf(fmaxf(s[0][r], s[1][r]), fmaxf(s[2][r], s[3][r]));
      rmax[r] = red_max16(rmax[r]);
    }
    float alpha[4];
    #pragma unroll
    for (int r = 0; r < 4; ++r) {
      const float mn = fmaxf(mrow[r], rmax[r]);
      alpha[r] = __expf(mrow[r] - mn);
      mrow[r] = mn;
    }
    #pragma unroll
    for (int ct = 0; ct < 4; ++ct) {
      #pragma unroll
      for (int r = 0; r < 4; ++r)
        s[ct][r] = __expf(s[ct][r] - mrow[r]);
    }
    #pragma unroll
    for (int r = 0; r < 4; ++r) {
      float ps = (s[0][r] + s[1][r]) + (s[2][r] + s[3][r]);
      ps = red_sum16(ps);
      lsum[r] = lsum[r] * alpha[r] + ps;
    }
    #pragma unroll
    for (int nt_ = 0; nt_ < 4; ++nt_) {
      #pragma unroll
      for (int r = 0; r < 4; ++r) O[nt_][r] *= alpha[r];
    }

    // ---- P -> bf16 -> Ps (wave-private rows; same-wave ordering suffices)
    #pragma unroll
    for (int ct = 0; ct < 4; ++ct) {
      #pragma unroll
      for (int r = 0; r < 4; ++r)
        *(unsigned short*)((char*)Ps + swzb(16*w + 4*lg + r, 16*ct + lr)) = f2bf(s[ct][r]);
    }
    bf16x8 pa[2];
    pa[0] = *(const bf16x8*)((const char*)Ps + swzb(16*w + lr, 8*lg));
    pa[1] = *(const bf16x8*)((const char*)Ps + swzb(16*w + lr, 8*lg + 32));

    // ---- O += P V (V fragments already in regs)
    #pragma unroll
    for (int nt_ = 0; nt_ < 4; ++nt_) {
      #pragma unroll
      for (int ks = 0; ks < 2; ++ks)
        O[nt_] = __builtin_amdgcn_mfma_f32_16x16x32_bf16(pa[ks], vv[nt_*2 + ks], O[nt_], 0, 0, 0);
    }

    __syncthreads();   // one barrier/step: drains KA[nb] gl16, flips buffers
  }

  // ---- epilogue
  if (np == 1) {
    #pragma unroll
    for (int r = 0; r < 4; ++r) {
      const float inv = 1.0f / lsum[r];
      #pragma unroll
      for (int nt_ = 0; nt_ < 4; ++nt_)
        outg[(bhOff + q0 + 16*w + 4*lg + r) * Dc + 16*nt_ + lr] = O[nt_][r] * inv;
    }
  } else {
    float* base = wsPart + ((((size_t)bh * 12 + (qi - 4)) * 3 + part) * 64) * 66;
    #pragma unroll
    for (int r = 0; r < 4; ++r) {
      float* rowp = base + (16*w + 4*lg + r) * 66;
      #pragma unroll
      for (int nt_ = 0; nt_ < 4; ++nt_)
        rowp[16*nt_ + lr] = O[nt_][r];
      if (lr == 0) { rowp[64] = mrow[r]; rowp[65] = lsum[r]; }
    }
  }
}

// merge 2-3 partials per (bh, qi>=4) row  [r9, validated]
__global__ __launch_bounds__(256) void attn_rpb_combine(
    const float* __restrict__ wsPart, float* __restrict__ outg)
{
  const int t = threadIdx.x;
  const int ridx = blockIdx.x * 4 + (t >> 6);
  const int d = t & 63;
  const int bh = ridx / 768;
  const int rem = ridx - bh * 768;
  const int qj = rem >> 6;
  const int rl = rem & 63;
  const float* p0 = wsPart + (((size_t)bh * 12 + qj) * 3 + 0) * 64 * 66 + (size_t)rl * 66;
  const float* p1 = p0 + 64 * 66;
  const float m0 = p0[64], l0 = p0[65];
  const float m1 = p1[64], l1 = p1[65];
  float m = fmaxf(m0, m1);
  float o, lc;
  if (qj >= 8) {
    const float* p2 = p1 + 64 * 66;
    const float m2 = p2[64], l2 = p2[65];
    m = fmaxf(m, m2);
    const float w0 = __expf(m0 - m), w1 = __expf(m1 - m), w2 = __expf(m2 - m);
    lc = l0 * w0 + l1 * w1 + l2 * w2;
    o  = p0[d] * w0 + p1[d] * w1 + p2[d] * w2;
  } else {
    const float w0 = __expf(m0 - m), w1 = __expf(m1 - m);
    lc = l0 * w0 + l1 * w1;
    o  = p0[d] * w0 + p1[d] * w1;
  }
  outg[((size_t)bh * Sc + (qj + 4) * 64 + rl) * Dc + d] = o / lc;
}

extern "C" void kernel_launch(void* const* d_in, const int* in_sizes, int n_in,
                              void* d_out, int out_size, void* d_ws, size_t ws_size,
                              hipStream_t stream) {
  const float* q  = (const float*)d_in[0];
  const float* k  = (const float*)d_in[1];
  const float* v  = (const float*)d_in[2];
  const int*   px = (const int*)d_in[3];
  const int*   py = (const int*)d_in[4];
  const int*   pz = (const int*)d_in[5];
  const float* bx = (const float*)d_in[6];
  const float* by = (const float*)d_in[7];
  const float* bz = (const float*)d_in[8];
  float* out = (float*)d_out;

  unsigned short* wsKA = (unsigned short*)d_ws;
  unsigned short* wsVt = (unsigned short*)((char*)d_ws + KA_BYTES);
  float* wsPart = (float*)((char*)d_ws + PART_OFF);

  prep<<<1024, 256, 0, stream>>>(k, v, px, py, bx, by, wsKA, wsVt);

  if (ws_size >= WS_SPLIT) {
    attn_rpb_mfma13<<<1024, NT, 0, stream>>>(q, px, py, pz, bz, wsKA, wsVt, out, wsPart, 1);
    attn_rpb_combine<<<6144, 256, 0, stream>>>(wsPart, out);
  } else {
    attn_rpb_mfma13<<<512, NT, 0, stream>>>(q, px, py, pz, bz, wsKA, wsVt, out, wsPart, 0);
  }
}